// Round 4
// baseline (325.563 us; speedup 1.0000x reference)
//
#include <hip/hip_runtime.h>
#include <hip/hip_bf16.h>
#include <math.h>

#define B_      2
#define L_      2048
#define DIM_    512
#define DINNER  1024
#define DTRANK  32
#define DSTATE  16
#define DCONV   4
#define BL      (B_ * L_)        // 4096
#define NCHUNK  32
#define CLEN    (L_ / NCHUNK)    // 64

typedef __attribute__((ext_vector_type(8))) short bf16x8;
typedef __attribute__((ext_vector_type(4))) float f32x4;

static __device__ __forceinline__ unsigned short f2bf(float f) {
  __hip_bfloat16 h = __float2bfloat16(f);
  return *(unsigned short*)&h;
}

// ---------------- weight fp32->bf16 conversion (3 tensors, one launch) ------
__global__ __launch_bounds__(256) void cvt3_kernel(
    const float* __restrict__ s0, const float* __restrict__ s1,
    const float* __restrict__ s2, __hip_bfloat16* __restrict__ d0,
    __hip_bfloat16* __restrict__ d1, __hip_bfloat16* __restrict__ d2) {
  int i = (blockIdx.x * 256 + threadIdx.x) * 4;   // over 1,638,400 elems
  const float* s; __hip_bfloat16* d; int off;
  if (i < 1048576)            { s = s0; d = d0; off = i; }
  else if (i < 1048576+65536) { s = s1; d = d1; off = i - 1048576; }
  else                        { s = s2; d = d2; off = i - 1114112; }
  float4 v = *(const float4*)(s + off);
  d[off + 0] = __float2bfloat16(v.x);
  d[off + 1] = __float2bfloat16(v.y);
  d[off + 2] = __float2bfloat16(v.z);
  d[off + 3] = __float2bfloat16(v.w);
}

// ---------------- LayerNorm: one wave per row, bf16 output ----------------
__global__ __launch_bounds__(64) void ln_kernel(
    const float* __restrict__ x, const float* __restrict__ g,
    const float* __restrict__ b, __hip_bfloat16* __restrict__ h) {
  int row = blockIdx.x;
  int lane = threadIdx.x;
  const float* xr = x + (size_t)row * DIM_;
  float v[8];
  float sum = 0.f;
#pragma unroll
  for (int i = 0; i < 8; i++) { v[i] = xr[lane + i * 64]; sum += v[i]; }
#pragma unroll
  for (int o = 32; o > 0; o >>= 1) sum += __shfl_xor(sum, o, 64);
  float mu = sum * (1.f / DIM_);
  float vs = 0.f;
#pragma unroll
  for (int i = 0; i < 8; i++) { float d = v[i] - mu; vs += d * d; }
#pragma unroll
  for (int o = 32; o > 0; o >>= 1) vs += __shfl_xor(vs, o, 64);
  float rstd = rsqrtf(vs * (1.f / DIM_) + 1e-5f);
  __hip_bfloat16* hr = h + (size_t)row * DIM_;
#pragma unroll
  for (int i = 0; i < 8; i++) {
    int c = lane + i * 64;
    hr[c] = __float2bfloat16((v[i] - mu) * rstd * g[c] + b[c]);
  }
}

// ---------------- bf16 MFMA GEMM, 128x128 tile: C = A[M,K] * B[N,K]^T ------
template <bool ADD_RES>
__global__ __launch_bounds__(256) void gemm_mfma_128(
    const __hip_bfloat16* __restrict__ A, int lda,
    const __hip_bfloat16* __restrict__ Bw, int ldb,
    const float* __restrict__ Res, int ldr,
    float* __restrict__ C, int ldc, int K) {
  constexpr int LDL = 72;
  __shared__ short As[128 * LDL];
  __shared__ short Bs[128 * LDL];
  int t = threadIdx.x;
  int n0 = blockIdx.x * 128, m0 = blockIdx.y * 128;
  int w = t >> 6, lane = t & 63;
  int wm = (w >> 1) * 64, wn = (w & 1) * 64;
  int l15 = lane & 15, quad = lane >> 4;
  int srow = t >> 3, scol = (t & 7) * 8;
  const short* Ag = (const short*)A + (size_t)(m0 + srow) * lda + scol;
  const short* Bg = (const short*)Bw + (size_t)(n0 + srow) * ldb + scol;
  f32x4 acc[4][4];
#pragma unroll
  for (int i = 0; i < 4; i++)
#pragma unroll
    for (int j = 0; j < 4; j++) acc[i][j] = (f32x4){0.f, 0.f, 0.f, 0.f};
  for (int k0 = 0; k0 < K; k0 += 64) {
    __syncthreads();
#pragma unroll
    for (int p = 0; p < 4; p++) {
      *(bf16x8*)&As[(srow + p * 32) * LDL + scol] =
          *(const bf16x8*)(Ag + (size_t)(p * 32) * lda + k0);
      *(bf16x8*)&Bs[(srow + p * 32) * LDL + scol] =
          *(const bf16x8*)(Bg + (size_t)(p * 32) * ldb + k0);
    }
    __syncthreads();
#pragma unroll
    for (int kk = 0; kk < 64; kk += 32) {
      bf16x8 af[4], bfr[4];
#pragma unroll
      for (int i = 0; i < 4; i++) {
        af[i] = *(const bf16x8*)&As[(wm + i * 16 + l15) * LDL + kk + quad * 8];
        bfr[i] = *(const bf16x8*)&Bs[(wn + i * 16 + l15) * LDL + kk + quad * 8];
      }
#pragma unroll
      for (int i = 0; i < 4; i++)
#pragma unroll
        for (int j = 0; j < 4; j++)
          acc[i][j] = __builtin_amdgcn_mfma_f32_16x16x32_bf16(
              af[i], bfr[j], acc[i][j], 0, 0, 0);
    }
  }
#pragma unroll
  for (int i = 0; i < 4; i++)
#pragma unroll
    for (int r = 0; r < 4; r++) {
      int row = m0 + wm + i * 16 + quad * 4 + r;
#pragma unroll
      for (int j = 0; j < 4; j++) {
        int col = n0 + wn + j * 16 + l15;
        float v = acc[i][j][r];
        if (ADD_RES) v += Res[(size_t)row * ldr + col];
        C[(size_t)row * ldc + col] = v;
      }
    }
}

// ---------------- bf16 MFMA GEMM, 64x64 tile, optional split-K (blockIdx.z) -
// K = per-slice K; slice z reads A/B at k-offset z*K, writes C + z*czs.
template <bool ADD_RES>
__global__ __launch_bounds__(256) void gemm_mfma_64(
    const __hip_bfloat16* __restrict__ A, int lda,
    const __hip_bfloat16* __restrict__ Bw, int ldb,
    const float* __restrict__ Res, int ldr,
    float* __restrict__ C, int ldc, int K, size_t czs) {
  constexpr int LDL = 72;
  __shared__ short As[64 * LDL];
  __shared__ short Bs[64 * LDL];
  int t = threadIdx.x;
  int n0 = blockIdx.x * 64, m0 = blockIdx.y * 64;
  size_t kbase = (size_t)blockIdx.z * K;
  int w = t >> 6, lane = t & 63;
  int wm = (w >> 1) * 32, wn = (w & 1) * 32;
  int l15 = lane & 15, quad = lane >> 4;
  int srow = t >> 3, scol = (t & 7) * 8;
  const short* Ag = (const short*)A + (size_t)(m0 + srow) * lda + scol + kbase;
  const short* Bg = (const short*)Bw + (size_t)(n0 + srow) * ldb + scol + kbase;
  f32x4 acc[2][2];
#pragma unroll
  for (int i = 0; i < 2; i++)
#pragma unroll
    for (int j = 0; j < 2; j++) acc[i][j] = (f32x4){0.f, 0.f, 0.f, 0.f};
  for (int k0 = 0; k0 < K; k0 += 64) {
    __syncthreads();
#pragma unroll
    for (int p = 0; p < 2; p++) {
      *(bf16x8*)&As[(srow + p * 32) * LDL + scol] =
          *(const bf16x8*)(Ag + (size_t)(p * 32) * lda + k0);
      *(bf16x8*)&Bs[(srow + p * 32) * LDL + scol] =
          *(const bf16x8*)(Bg + (size_t)(p * 32) * ldb + k0);
    }
    __syncthreads();
#pragma unroll
    for (int kk = 0; kk < 64; kk += 32) {
      bf16x8 af[2], bfr[2];
#pragma unroll
      for (int i = 0; i < 2; i++) {
        af[i] = *(const bf16x8*)&As[(wm + i * 16 + l15) * LDL + kk + quad * 8];
        bfr[i] = *(const bf16x8*)&Bs[(wn + i * 16 + l15) * LDL + kk + quad * 8];
      }
#pragma unroll
      for (int i = 0; i < 2; i++)
#pragma unroll
        for (int j = 0; j < 2; j++)
          acc[i][j] = __builtin_amdgcn_mfma_f32_16x16x32_bf16(
              af[i], bfr[j], acc[i][j], 0, 0, 0);
    }
  }
  float* Cz = C + czs * blockIdx.z;
#pragma unroll
  for (int i = 0; i < 2; i++)
#pragma unroll
    for (int r = 0; r < 4; r++) {
      int row = m0 + wm + i * 16 + quad * 4 + r;
#pragma unroll
      for (int j = 0; j < 2; j++) {
        int col = n0 + wn + j * 16 + l15;
        float v = acc[i][j][r];
        if (ADD_RES) v += Res[(size_t)row * ldr + col];
        Cz[(size_t)row * ldc + col] = v;
      }
    }
}

// ---------------- split-K reduce for proj: proj = sum of 4 slices ----------
__global__ __launch_bounds__(256) void reduce4_kernel(
    const float* __restrict__ pp, float* __restrict__ proj) {
  int i = blockIdx.x * 256 + threadIdx.x;   // over 262144
  proj[i] = pp[i] + pp[i + 262144] + pp[i + 2 * 262144] + pp[i + 3 * 262144];
}

// ------- causal depthwise conv (4 taps) + SiLU, float4 over d --------------
// also computes gate = SiLU(z) in-place over the z-half of xz.
__global__ __launch_bounds__(256) void conv_silu_kernel(
    float* __restrict__ xz, const float* __restrict__ cw,
    const float* __restrict__ cb, float* __restrict__ xc,
    __hip_bfloat16* __restrict__ xc_bf) {
  int idx = blockIdx.x * 256 + threadIdx.x;   // over BL*DINNER/4
  int d4 = (idx & 255) * 4;
  int bl = idx >> 8;
  int l = bl & (L_ - 1);
  float* base = xz + (size_t)bl * (2 * DINNER) + d4;
  float4 acc = *(const float4*)(cb + d4);
  float4 w0 = *(const float4*)(cw + (d4 + 0) * 4);
  float4 w1 = *(const float4*)(cw + (d4 + 1) * 4);
  float4 w2 = *(const float4*)(cw + (d4 + 2) * 4);
  float4 w3 = *(const float4*)(cw + (d4 + 3) * 4);
  if (l >= 3) {
    float4 r = *(const float4*)(base - 3 * 2 * DINNER);
    acc.x += r.x * w0.x; acc.y += r.y * w1.x; acc.z += r.z * w2.x; acc.w += r.w * w3.x;
  }
  if (l >= 2) {
    float4 r = *(const float4*)(base - 2 * 2 * DINNER);
    acc.x += r.x * w0.y; acc.y += r.y * w1.y; acc.z += r.z * w2.y; acc.w += r.w * w3.y;
  }
  if (l >= 1) {
    float4 r = *(const float4*)(base - 1 * 2 * DINNER);
    acc.x += r.x * w0.z; acc.y += r.y * w1.z; acc.z += r.z * w2.z; acc.w += r.w * w3.z;
  }
  {
    float4 r = *(const float4*)(base);
    acc.x += r.x * w0.w; acc.y += r.y * w1.w; acc.z += r.z * w2.w; acc.w += r.w * w3.w;
  }
  float4 v;
  v.x = acc.x / (1.f + __expf(-acc.x));
  v.y = acc.y / (1.f + __expf(-acc.y));
  v.z = acc.z / (1.f + __expf(-acc.z));
  v.w = acc.w / (1.f + __expf(-acc.w));
  *(float4*)(xc + (size_t)bl * DINNER + d4) = v;
  ushort4 hb;
  hb.x = f2bf(v.x); hb.y = f2bf(v.y); hb.z = f2bf(v.z); hb.w = f2bf(v.w);
  *(ushort4*)(xc_bf + (size_t)bl * DINNER + d4) = hb;
  // gate = SiLU(z), in place
  float4 zv = *(const float4*)(base + DINNER);
  float4 gv;
  gv.x = zv.x / (1.f + __expf(-zv.x));
  gv.y = zv.y / (1.f + __expf(-zv.y));
  gv.z = zv.z / (1.f + __expf(-zv.z));
  gv.w = zv.w / (1.f + __expf(-zv.w));
  *(float4*)(base + DINNER) = gv;
}

// ---------------- dt = softplus(proj[:, :32] @ W_dt^T + b_dt) --------------
// grid 1024: (256 row-groups of 16) x (4 d-groups of 256)
__global__ __launch_bounds__(256) void dt_kernel(
    const float* __restrict__ proj, const float* __restrict__ Wdt,
    const float* __restrict__ bdt, float* __restrict__ dt) {
  int blk = blockIdx.x;
  int dgrp = blk & 3;
  int bl0 = (blk >> 2) * 16;
  int d = dgrp * 256 + threadIdx.x;
  __shared__ float pr[16 * 32];
  for (int i = threadIdx.x; i < 16 * 32; i += 256) {   // FIX: strided loop,
    int row = i >> 5, col = i & 31;                    // 256 threads load 512
    pr[i] = proj[(size_t)(bl0 + row) * 64 + col];
  }
  float w[32];
#pragma unroll
  for (int r4 = 0; r4 < 8; r4++) {
    float4 wv = *(const float4*)(Wdt + (size_t)d * 32 + r4 * 4);
    w[r4 * 4 + 0] = wv.x; w[r4 * 4 + 1] = wv.y;
    w[r4 * 4 + 2] = wv.z; w[r4 * 4 + 3] = wv.w;
  }
  float bias = bdt[d];
  __syncthreads();
  for (int row = 0; row < 16; row++) {
    float acc = bias;
#pragma unroll
    for (int r4 = 0; r4 < 8; r4++) {
      float4 pv = *(const float4*)&pr[row * 32 + r4 * 4];
      acc += pv.x * w[r4 * 4 + 0] + pv.y * w[r4 * 4 + 1] +
             pv.z * w[r4 * 4 + 2] + pv.w * w[r4 * 4 + 3];
    }
    float sp = (acc > 20.f) ? acc : log1pf(__expf(acc));
    dt[(size_t)(bl0 + row) * DINNER + d] = sp;
  }
}

// ---- scan pass 1, (d,n)-parallel: per-chunk decay T and end-state E -------
// grid 4096 = b(2) x c(32) x dgrp(64); block = 16 d x 16 n
__global__ __launch_bounds__(256) void scan1_kernel(
    const float* __restrict__ dt, const float* __restrict__ xc,
    const float* __restrict__ proj, const float* __restrict__ A_log,
    float* __restrict__ T, float* __restrict__ E) {
  int bid = blockIdx.x;
  int dgrp = bid & 63;
  int c = (bid >> 6) & (NCHUNK - 1);
  int b = bid >> 11;
  int n = threadIdx.x & 15;
  int d = dgrp * 16 + (threadIdx.x >> 4);
  float Aa = -__expf(A_log[(size_t)d * 16 + n]);
  float Tn = 1.f, En = 0.f;
  int l0 = c * CLEN;
  for (int l = l0; l < l0 + CLEN; l++) {
    int bl = b * L_ + l;
    float dtv = dt[(size_t)bl * DINNER + d];
    float xv = xc[(size_t)bl * DINNER + d];
    float Bv = proj[(size_t)bl * 64 + 32 + n];
    float dA = __expf(dtv * Aa);
    Tn *= dA;
    En = En * dA + dtv * xv * Bv;
  }
  size_t o = (((size_t)b * NCHUNK + c) * DINNER + d) * 16 + n;
  T[o] = Tn; E[o] = En;
}

// ---------------- chunk combine: batch loads, serial math, batch stores ----
__global__ __launch_bounds__(256) void combine_kernel(
    float* __restrict__ T, const float* __restrict__ E) {
  int idx = blockIdx.x * 256 + threadIdx.x;   // over B*DINNER*16 = 32768
  int b = idx >> 14;
  int dn = idx & 16383;
  size_t base = (size_t)b * NCHUNK * (DINNER * 16) + dn;
  float t[NCHUNK], e[NCHUNK];
#pragma unroll
  for (int c = 0; c < NCHUNK; c++) {
    t[c] = T[base + (size_t)c * (DINNER * 16)];
    e[c] = E[base + (size_t)c * (DINNER * 16)];
  }
  float s = 0.f;
#pragma unroll
  for (int c = 0; c < NCHUNK; c++) {
    T[base + (size_t)c * (DINNER * 16)] = s;
    s = t[c] * s + e[c];
  }
}

// ---- scan pass 2, (d,n)-parallel: replay + y + D-skip + gate --------------
// y = sum_n s*C via shfl-xor over 16-lane groups; gate pre-computed (SiLU(z))
// y written bf16 into the dead xp half of xz (row stride 4096 shorts).
__global__ __launch_bounds__(256) void scan2_kernel(
    const float* __restrict__ dt, const float* __restrict__ xc,
    const float* __restrict__ proj, const float* __restrict__ A_log,
    const float* __restrict__ Sstart, const float* __restrict__ Dp,
    float* __restrict__ xz) {
  int bid = blockIdx.x;
  int dgrp = bid & 63;
  int c = (bid >> 6) & (NCHUNK - 1);
  int b = bid >> 11;
  int n = threadIdx.x & 15;
  int d = dgrp * 16 + (threadIdx.x >> 4);
  float Aa = -__expf(A_log[(size_t)d * 16 + n]);
  size_t o = (((size_t)b * NCHUNK + c) * DINNER + d) * 16 + n;
  float s = Sstart[o];
  float Dv = Dp[d];
  __hip_bfloat16* ybf = (__hip_bfloat16*)xz;
  int l0 = c * CLEN;
  for (int l = l0; l < l0 + CLEN; l++) {
    int bl = b * L_ + l;
    float dtv = dt[(size_t)bl * DINNER + d];
    float xv = xc[(size_t)bl * DINNER + d];
    float Bv = proj[(size_t)bl * 64 + 32 + n];
    float Cv = proj[(size_t)bl * 64 + 48 + n];
    float dA = __expf(dtv * Aa);
    s = s * dA + dtv * xv * Bv;
    float y = s * Cv;
    y += __shfl_xor(y, 8, 64);
    y += __shfl_xor(y, 4, 64);
    y += __shfl_xor(y, 2, 64);
    y += __shfl_xor(y, 1, 64);
    if (n == 0) {
      float gate = xz[(size_t)bl * (2 * DINNER) + DINNER + d];
      ybf[(size_t)bl * 4096 + d] = __float2bfloat16((y + xv * Dv) * gate);
    }
  }
}

extern "C" void kernel_launch(void* const* d_in, const int* in_sizes, int n_in,
                              void* d_out, int out_size, void* d_ws, size_t ws_size,
                              hipStream_t stream) {
  const float* x      = (const float*)d_in[0];
  const float* ln_g   = (const float*)d_in[1];
  const float* ln_b   = (const float*)d_in[2];
  const float* W_in   = (const float*)d_in[3];
  const float* conv_w = (const float*)d_in[4];
  const float* conv_b = (const float*)d_in[5];
  const float* W_xprj = (const float*)d_in[6];
  const float* W_dt   = (const float*)d_in[7];
  const float* b_dt   = (const float*)d_in[8];
  const float* A_log  = (const float*)d_in[9];
  const float* Dp     = (const float*)d_in[10];
  const float* W_out  = (const float*)d_in[11];
  float* out = (float*)d_out;

  // workspace layout (floats) — total 84.0 MB (same as R1-proven footprint)
  float* ws    = (float*)d_ws;
  float* xz    = ws;                       //  8,388,608 f (y_bf reuses xp half)
  float* xc    = xz + 8388608;             //  4,194,304 f
  float* R     = xc + 4194304;             //  2,097,152 f (xc_bf, then T+E)
  float* proj  = R + 2097152;              //    262,144 f
  float* dtb   = proj + 262144;            //  4,194,304 f (pp overlaps head)
  float* hbf_f = dtb + 4194304;            //  1,048,576 f (h_bf)
  float* wbf   = hbf_f + 1048576;          //    819,200 f (bf16 weights)

  __hip_bfloat16* xc_bf = (__hip_bfloat16*)R;
  float* T = R;
  float* E = R + 1048576;
  float* pp = dtb;                         // 1,048,576 f split-K partials
  __hip_bfloat16* h_bf  = (__hip_bfloat16*)hbf_f;
  __hip_bfloat16* Wb_in = (__hip_bfloat16*)wbf;
  __hip_bfloat16* Wb_xp = Wb_in + 1048576;
  __hip_bfloat16* Wb_out = Wb_xp + 65536;
  __hip_bfloat16* y_bf  = (__hip_bfloat16*)xz;   // lda = 4096 shorts

  // 0. weights -> bf16
  cvt3_kernel<<<1600, 256, 0, stream>>>(W_in, W_xprj, W_out, Wb_in, Wb_xp, Wb_out);
  // 1. LayerNorm -> bf16 h
  ln_kernel<<<BL, 64, 0, stream>>>(x, ln_g, ln_b, h_bf);
  // 2. xz = h @ W_in^T   (M=4096, N=2048, K=512)  [MFMA 128x128]
  gemm_mfma_128<false><<<dim3(2 * DINNER / 128, BL / 128), 256, 0, stream>>>(
      h_bf, DIM_, Wb_in, DIM_, nullptr, 0, xz, 2 * DINNER, DIM_);
  // 3. conv + SiLU -> xc/xc_bf; gate = SiLU(z) in place
  conv_silu_kernel<<<(BL * DINNER / 4) / 256, 256, 0, stream>>>(
      xz, conv_w, conv_b, xc, xc_bf);
  // 4. proj = xc @ W_xproj^T (M=4096, N=64, K=1024)  [MFMA 64x64, split-K=4]
  gemm_mfma_64<false><<<dim3(1, BL / 64, 4), 256, 0, stream>>>(
      xc_bf, DINNER, Wb_xp, DINNER, nullptr, 0, pp, 64, 256, 262144);
  reduce4_kernel<<<1024, 256, 0, stream>>>(pp, proj);
  // 5. dt = softplus(proj[:, :32] @ W_dt^T + b_dt)  (overwrites pp region)
  dt_kernel<<<(BL / 16) * 4, 256, 0, stream>>>(proj, W_dt, b_dt, dtb);
  // 6. chunked scan, (d,n)-parallel
  scan1_kernel<<<B_ * NCHUNK * 64, 256, 0, stream>>>(dtb, xc, proj, A_log, T, E);
  combine_kernel<<<(B_ * DINNER * 16) / 256, 256, 0, stream>>>(T, E);
  scan2_kernel<<<B_ * NCHUNK * 64, 256, 0, stream>>>(dtb, xc, proj, A_log, T, Dp, xz);
  // 7. out = x + y @ W_out^T (M=4096, N=512, K=1024)  [MFMA 64x64, fused res]
  gemm_mfma_64<true><<<dim3(DIM_ / 64, BL / 64, 1), 256, 0, stream>>>(
      y_bf, 4096, Wb_out, DINNER, x, DIM_, out, DIM_, DINNER, 0);
}

// Round 5
// 253.315 us; speedup vs baseline: 1.2852x; 1.2852x over previous
//
#include <hip/hip_runtime.h>
#include <hip/hip_bf16.h>
#include <math.h>

#define B_      2
#define L_      2048
#define DIM_    512
#define DINNER  1024
#define DTRANK  32
#define DSTATE  16
#define DCONV   4
#define BL      (B_ * L_)        // 4096
#define NCHUNK  64
#define CLEN    (L_ / NCHUNK)    // 32

typedef __attribute__((ext_vector_type(8))) short bf16x8;
typedef __attribute__((ext_vector_type(4))) float f32x4;

static __device__ __forceinline__ unsigned short f2bf(float f) {
  __hip_bfloat16 h = __float2bfloat16(f);
  return *(unsigned short*)&h;
}

// ---------------- weight fp32->bf16 conversion (3 tensors, one launch) ------
__global__ __launch_bounds__(256) void cvt3_kernel(
    const float* __restrict__ s0, const float* __restrict__ s1,
    const float* __restrict__ s2, __hip_bfloat16* __restrict__ d0,
    __hip_bfloat16* __restrict__ d1, __hip_bfloat16* __restrict__ d2) {
  int i = (blockIdx.x * 256 + threadIdx.x) * 4;   // over 1,638,400 elems
  const float* s; __hip_bfloat16* d; int off;
  if (i < 1048576)            { s = s0; d = d0; off = i; }
  else if (i < 1048576+65536) { s = s1; d = d1; off = i - 1048576; }
  else                        { s = s2; d = d2; off = i - 1114112; }
  float4 v = *(const float4*)(s + off);
  d[off + 0] = __float2bfloat16(v.x);
  d[off + 1] = __float2bfloat16(v.y);
  d[off + 2] = __float2bfloat16(v.z);
  d[off + 3] = __float2bfloat16(v.w);
}

// ---------------- LayerNorm: one wave per row, bf16 output ----------------
__global__ __launch_bounds__(64) void ln_kernel(
    const float* __restrict__ x, const float* __restrict__ g,
    const float* __restrict__ b, __hip_bfloat16* __restrict__ h) {
  int row = blockIdx.x;
  int lane = threadIdx.x;
  const float* xr = x + (size_t)row * DIM_;
  float v[8];
  float sum = 0.f;
#pragma unroll
  for (int i = 0; i < 8; i++) { v[i] = xr[lane + i * 64]; sum += v[i]; }
#pragma unroll
  for (int o = 32; o > 0; o >>= 1) sum += __shfl_xor(sum, o, 64);
  float mu = sum * (1.f / DIM_);
  float vs = 0.f;
#pragma unroll
  for (int i = 0; i < 8; i++) { float d = v[i] - mu; vs += d * d; }
#pragma unroll
  for (int o = 32; o > 0; o >>= 1) vs += __shfl_xor(vs, o, 64);
  float rstd = rsqrtf(vs * (1.f / DIM_) + 1e-5f);
  __hip_bfloat16* hr = h + (size_t)row * DIM_;
#pragma unroll
  for (int i = 0; i < 8; i++) {
    int c = lane + i * 64;
    hr[c] = __float2bfloat16((v[i] - mu) * rstd * g[c] + b[c]);
  }
}

// ---------------- bf16 MFMA GEMM, 128x128 tile: C = A[M,K] * B[N,K]^T ------
template <bool ADD_RES>
__global__ __launch_bounds__(256) void gemm_mfma_128(
    const __hip_bfloat16* __restrict__ A, int lda,
    const __hip_bfloat16* __restrict__ Bw, int ldb,
    const float* __restrict__ Res, int ldr,
    float* __restrict__ C, int ldc, int K) {
  constexpr int LDL = 72;
  __shared__ short As[128 * LDL];
  __shared__ short Bs[128 * LDL];
  int t = threadIdx.x;
  int n0 = blockIdx.x * 128, m0 = blockIdx.y * 128;
  int w = t >> 6, lane = t & 63;
  int wm = (w >> 1) * 64, wn = (w & 1) * 64;
  int l15 = lane & 15, quad = lane >> 4;
  int srow = t >> 3, scol = (t & 7) * 8;
  const short* Ag = (const short*)A + (size_t)(m0 + srow) * lda + scol;
  const short* Bg = (const short*)Bw + (size_t)(n0 + srow) * ldb + scol;
  f32x4 acc[4][4];
#pragma unroll
  for (int i = 0; i < 4; i++)
#pragma unroll
    for (int j = 0; j < 4; j++) acc[i][j] = (f32x4){0.f, 0.f, 0.f, 0.f};
  for (int k0 = 0; k0 < K; k0 += 64) {
    __syncthreads();
#pragma unroll
    for (int p = 0; p < 4; p++) {
      *(bf16x8*)&As[(srow + p * 32) * LDL + scol] =
          *(const bf16x8*)(Ag + (size_t)(p * 32) * lda + k0);
      *(bf16x8*)&Bs[(srow + p * 32) * LDL + scol] =
          *(const bf16x8*)(Bg + (size_t)(p * 32) * ldb + k0);
    }
    __syncthreads();
#pragma unroll
    for (int kk = 0; kk < 64; kk += 32) {
      bf16x8 af[4], bfr[4];
#pragma unroll
      for (int i = 0; i < 4; i++) {
        af[i] = *(const bf16x8*)&As[(wm + i * 16 + l15) * LDL + kk + quad * 8];
        bfr[i] = *(const bf16x8*)&Bs[(wn + i * 16 + l15) * LDL + kk + quad * 8];
      }
#pragma unroll
      for (int i = 0; i < 4; i++)
#pragma unroll
        for (int j = 0; j < 4; j++)
          acc[i][j] = __builtin_amdgcn_mfma_f32_16x16x32_bf16(
              af[i], bfr[j], acc[i][j], 0, 0, 0);
    }
  }
#pragma unroll
  for (int i = 0; i < 4; i++)
#pragma unroll
    for (int r = 0; r < 4; r++) {
      int row = m0 + wm + i * 16 + quad * 4 + r;
#pragma unroll
      for (int j = 0; j < 4; j++) {
        int col = n0 + wn + j * 16 + l15;
        float v = acc[i][j][r];
        if (ADD_RES) v += Res[(size_t)row * ldr + col];
        C[(size_t)row * ldc + col] = v;
      }
    }
}

// ---------------- bf16 MFMA GEMM, 64x64 tile, optional split-K (blockIdx.z) -
template <bool ADD_RES>
__global__ __launch_bounds__(256) void gemm_mfma_64(
    const __hip_bfloat16* __restrict__ A, int lda,
    const __hip_bfloat16* __restrict__ Bw, int ldb,
    const float* __restrict__ Res, int ldr,
    float* __restrict__ C, int ldc, int K, size_t czs) {
  constexpr int LDL = 72;
  __shared__ short As[64 * LDL];
  __shared__ short Bs[64 * LDL];
  int t = threadIdx.x;
  int n0 = blockIdx.x * 64, m0 = blockIdx.y * 64;
  size_t kbase = (size_t)blockIdx.z * K;
  int w = t >> 6, lane = t & 63;
  int wm = (w >> 1) * 32, wn = (w & 1) * 32;
  int l15 = lane & 15, quad = lane >> 4;
  int srow = t >> 3, scol = (t & 7) * 8;
  const short* Ag = (const short*)A + (size_t)(m0 + srow) * lda + scol + kbase;
  const short* Bg = (const short*)Bw + (size_t)(n0 + srow) * ldb + scol + kbase;
  f32x4 acc[2][2];
#pragma unroll
  for (int i = 0; i < 2; i++)
#pragma unroll
    for (int j = 0; j < 2; j++) acc[i][j] = (f32x4){0.f, 0.f, 0.f, 0.f};
  for (int k0 = 0; k0 < K; k0 += 64) {
    __syncthreads();
#pragma unroll
    for (int p = 0; p < 2; p++) {
      *(bf16x8*)&As[(srow + p * 32) * LDL + scol] =
          *(const bf16x8*)(Ag + (size_t)(p * 32) * lda + k0);
      *(bf16x8*)&Bs[(srow + p * 32) * LDL + scol] =
          *(const bf16x8*)(Bg + (size_t)(p * 32) * ldb + k0);
    }
    __syncthreads();
#pragma unroll
    for (int kk = 0; kk < 64; kk += 32) {
      bf16x8 af[2], bfr[2];
#pragma unroll
      for (int i = 0; i < 2; i++) {
        af[i] = *(const bf16x8*)&As[(wm + i * 16 + l15) * LDL + kk + quad * 8];
        bfr[i] = *(const bf16x8*)&Bs[(wn + i * 16 + l15) * LDL + kk + quad * 8];
      }
#pragma unroll
      for (int i = 0; i < 2; i++)
#pragma unroll
        for (int j = 0; j < 2; j++)
          acc[i][j] = __builtin_amdgcn_mfma_f32_16x16x32_bf16(
              af[i], bfr[j], acc[i][j], 0, 0, 0);
    }
  }
  float* Cz = C + czs * blockIdx.z;
#pragma unroll
  for (int i = 0; i < 2; i++)
#pragma unroll
    for (int r = 0; r < 4; r++) {
      int row = m0 + wm + i * 16 + quad * 4 + r;
#pragma unroll
      for (int j = 0; j < 2; j++) {
        int col = n0 + wn + j * 16 + l15;
        float v = acc[i][j][r];
        if (ADD_RES) v += Res[(size_t)row * ldr + col];
        Cz[(size_t)row * ldc + col] = v;
      }
    }
}

// ---------------- split-K reduce for proj: proj = sum of 4 slices ----------
__global__ __launch_bounds__(256) void reduce4_kernel(
    const float* __restrict__ pp, float* __restrict__ proj) {
  int i = blockIdx.x * 256 + threadIdx.x;   // over 262144
  proj[i] = pp[i] + pp[i + 262144] + pp[i + 2 * 262144] + pp[i + 3 * 262144];
}

// ------- causal depthwise conv (4 taps) + SiLU, float4 over d --------------
// outputs xc in bf16 only; also gate = SiLU(z) in-place over z-half of xz.
__global__ __launch_bounds__(256) void conv_silu_kernel(
    float* __restrict__ xz, const float* __restrict__ cw,
    const float* __restrict__ cb, __hip_bfloat16* __restrict__ xc_bf) {
  int idx = blockIdx.x * 256 + threadIdx.x;   // over BL*DINNER/4
  int d4 = (idx & 255) * 4;
  int bl = idx >> 8;
  int l = bl & (L_ - 1);
  float* base = xz + (size_t)bl * (2 * DINNER) + d4;
  float4 acc = *(const float4*)(cb + d4);
  float4 w0 = *(const float4*)(cw + (d4 + 0) * 4);
  float4 w1 = *(const float4*)(cw + (d4 + 1) * 4);
  float4 w2 = *(const float4*)(cw + (d4 + 2) * 4);
  float4 w3 = *(const float4*)(cw + (d4 + 3) * 4);
  if (l >= 3) {
    float4 r = *(const float4*)(base - 3 * 2 * DINNER);
    acc.x += r.x * w0.x; acc.y += r.y * w1.x; acc.z += r.z * w2.x; acc.w += r.w * w3.x;
  }
  if (l >= 2) {
    float4 r = *(const float4*)(base - 2 * 2 * DINNER);
    acc.x += r.x * w0.y; acc.y += r.y * w1.y; acc.z += r.z * w2.y; acc.w += r.w * w3.y;
  }
  if (l >= 1) {
    float4 r = *(const float4*)(base - 1 * 2 * DINNER);
    acc.x += r.x * w0.z; acc.y += r.y * w1.z; acc.z += r.z * w2.z; acc.w += r.w * w3.z;
  }
  {
    float4 r = *(const float4*)(base);
    acc.x += r.x * w0.w; acc.y += r.y * w1.w; acc.z += r.z * w2.w; acc.w += r.w * w3.w;
  }
  float4 v;
  v.x = acc.x / (1.f + __expf(-acc.x));
  v.y = acc.y / (1.f + __expf(-acc.y));
  v.z = acc.z / (1.f + __expf(-acc.z));
  v.w = acc.w / (1.f + __expf(-acc.w));
  ushort4 hb;
  hb.x = f2bf(v.x); hb.y = f2bf(v.y); hb.z = f2bf(v.z); hb.w = f2bf(v.w);
  *(ushort4*)(xc_bf + (size_t)bl * DINNER + d4) = hb;
  // gate = SiLU(z), in place
  float4 zv = *(const float4*)(base + DINNER);
  float4 gv;
  gv.x = zv.x / (1.f + __expf(-zv.x));
  gv.y = zv.y / (1.f + __expf(-zv.y));
  gv.z = zv.z / (1.f + __expf(-zv.z));
  gv.w = zv.w / (1.f + __expf(-zv.w));
  *(float4*)(base + DINNER) = gv;
}

// ---------------- dt = softplus(proj[:, :32] @ W_dt^T + b_dt) --------------
__global__ __launch_bounds__(256) void dt_kernel(
    const float* __restrict__ proj, const float* __restrict__ Wdt,
    const float* __restrict__ bdt, float* __restrict__ dt) {
  int blk = blockIdx.x;
  int dgrp = blk & 3;
  int bl0 = (blk >> 2) * 16;
  int d = dgrp * 256 + threadIdx.x;
  __shared__ float pr[16 * 32];
  for (int i = threadIdx.x; i < 16 * 32; i += 256) {
    int row = i >> 5, col = i & 31;
    pr[i] = proj[(size_t)(bl0 + row) * 64 + col];
  }
  float w[32];
#pragma unroll
  for (int r4 = 0; r4 < 8; r4++) {
    float4 wv = *(const float4*)(Wdt + (size_t)d * 32 + r4 * 4);
    w[r4 * 4 + 0] = wv.x; w[r4 * 4 + 1] = wv.y;
    w[r4 * 4 + 2] = wv.z; w[r4 * 4 + 3] = wv.w;
  }
  float bias = bdt[d];
  __syncthreads();
  for (int row = 0; row < 16; row++) {
    float acc = bias;
#pragma unroll
    for (int r4 = 0; r4 < 8; r4++) {
      float4 pv = *(const float4*)&pr[row * 32 + r4 * 4];
      acc += pv.x * w[r4 * 4 + 0] + pv.y * w[r4 * 4 + 1] +
             pv.z * w[r4 * 4 + 2] + pv.w * w[r4 * 4 + 3];
    }
    float sp = (acc > 20.f) ? acc : log1pf(__expf(acc));
    dt[(size_t)(bl0 + row) * DINNER + d] = sp;
  }
}

// ---- scan pass 1, (d,n)-parallel: per-chunk decay T and end-state E -------
// grid 8192 = b(2) x c(64) x dgrp(64); block = 16 d x 16 n; CLEN=32
__global__ __launch_bounds__(256) void scan1_kernel(
    const float* __restrict__ dt, const __hip_bfloat16* __restrict__ xc_bf,
    const float* __restrict__ proj, const float* __restrict__ A_log,
    float* __restrict__ T, float* __restrict__ E) {
  int bid = blockIdx.x;
  int dgrp = bid & 63;
  int c = (bid >> 6) & (NCHUNK - 1);
  int b = bid >> 12;
  int n = threadIdx.x & 15;
  int d = dgrp * 16 + (threadIdx.x >> 4);
  float Aa = -__expf(A_log[(size_t)d * 16 + n]);
  float Tn = 1.f, En = 0.f;
  int l0 = c * CLEN;
  for (int l = l0; l < l0 + CLEN; l++) {
    int bl = b * L_ + l;
    float dtv = dt[(size_t)bl * DINNER + d];
    float xv = __bfloat162float(xc_bf[(size_t)bl * DINNER + d]);
    float Bv = proj[(size_t)bl * 64 + 32 + n];
    float dA = __expf(dtv * Aa);
    Tn *= dA;
    En = En * dA + dtv * xv * Bv;
  }
  size_t o = (((size_t)b * NCHUNK + c) * DINNER + d) * 16 + n;
  T[o] = Tn; E[o] = En;
}

// ---------------- chunk combine over 64 chunks, 4 register-batches of 16 ----
__global__ __launch_bounds__(256) void combine_kernel(
    float* __restrict__ T, const float* __restrict__ E) {
  int idx = blockIdx.x * 256 + threadIdx.x;   // over B*DINNER*16 = 32768
  int b = idx >> 14;
  int dn = idx & 16383;
  size_t base = (size_t)b * NCHUNK * (DINNER * 16) + dn;
  float s = 0.f;
#pragma unroll
  for (int batch = 0; batch < 4; batch++) {
    float t[16], e[16];
#pragma unroll
    for (int j = 0; j < 16; j++) {
      size_t o = base + (size_t)(batch * 16 + j) * (DINNER * 16);
      t[j] = T[o]; e[j] = E[o];
    }
#pragma unroll
    for (int j = 0; j < 16; j++) {
      T[base + (size_t)(batch * 16 + j) * (DINNER * 16)] = s;
      s = t[j] * s + e[j];
    }
  }
}

// ---- scan pass 2: 16 states per thread, in-register y reduction -----------
// grid 512 = b(2) x c(64) x dgrp(4); block = 256 d. B/C tiles staged in LDS.
// y written bf16 into the dead xp head of xz rows (stride 4096 shorts).
__global__ __launch_bounds__(256) void scan2_kernel(
    const float* __restrict__ dt, const __hip_bfloat16* __restrict__ xc_bf,
    const float* __restrict__ proj, const float* __restrict__ A_log,
    const float* __restrict__ Sstart, const float* __restrict__ Dp,
    float* __restrict__ xz) {
  int bid = blockIdx.x;
  int dgrp = bid & 3;
  int c = (bid >> 2) & (NCHUNK - 1);
  int b = bid >> 8;
  int d = dgrp * 256 + threadIdx.x;
  int l0 = c * CLEN;
  __shared__ float Bs[CLEN * 16];
  __shared__ float Cs[CLEN * 16];
  for (int i = threadIdx.x; i < CLEN * 16; i += 256) {
    int row = i >> 4, nn = i & 15;
    const float* pr = proj + (size_t)(b * L_ + l0 + row) * 64;
    Bs[i] = pr[32 + nn];
    Cs[i] = pr[48 + nn];
  }
  float Aa[16], s[16];
  size_t sb = (((size_t)b * NCHUNK + c) * DINNER + d) * 16;
#pragma unroll
  for (int q = 0; q < 4; q++) {
    float4 av; // A_log row is 16 consecutive floats per d
    av = *(const float4*)(A_log + (size_t)d * 16 + q * 4);
    Aa[q * 4 + 0] = -__expf(av.x); Aa[q * 4 + 1] = -__expf(av.y);
    Aa[q * 4 + 2] = -__expf(av.z); Aa[q * 4 + 3] = -__expf(av.w);
    float4 sv = *(const float4*)(Sstart + sb + q * 4);
    s[q * 4 + 0] = sv.x; s[q * 4 + 1] = sv.y;
    s[q * 4 + 2] = sv.z; s[q * 4 + 3] = sv.w;
  }
  float Dv = Dp[d];
  __hip_bfloat16* ybf = (__hip_bfloat16*)xz;
  __syncthreads();
  for (int l = l0; l < l0 + CLEN; l++) {
    int bl = b * L_ + l;
    float dtv = dt[(size_t)bl * DINNER + d];
    float xv = __bfloat162float(xc_bf[(size_t)bl * DINNER + d]);
    float dx = dtv * xv;
    int lrow = (l - l0) * 16;
    float y = 0.f;
#pragma unroll
    for (int n = 0; n < 16; n++) {
      float dA = __expf(dtv * Aa[n]);
      s[n] = s[n] * dA + dx * Bs[lrow + n];
      y += s[n] * Cs[lrow + n];
    }
    float gate = xz[(size_t)bl * (2 * DINNER) + DINNER + d];
    ybf[(size_t)bl * 4096 + d] = __float2bfloat16((y + xv * Dv) * gate);
  }
}

extern "C" void kernel_launch(void* const* d_in, const int* in_sizes, int n_in,
                              void* d_out, int out_size, void* d_ws, size_t ws_size,
                              hipStream_t stream) {
  const float* x      = (const float*)d_in[0];
  const float* ln_g   = (const float*)d_in[1];
  const float* ln_b   = (const float*)d_in[2];
  const float* W_in   = (const float*)d_in[3];
  const float* conv_w = (const float*)d_in[4];
  const float* conv_b = (const float*)d_in[5];
  const float* W_xprj = (const float*)d_in[6];
  const float* W_dt   = (const float*)d_in[7];
  const float* b_dt   = (const float*)d_in[8];
  const float* A_log  = (const float*)d_in[9];
  const float* Dp     = (const float*)d_in[10];
  const float* W_out  = (const float*)d_in[11];
  float* out = (float*)d_out;

  // workspace layout (floats) — total 84.0 MB (same footprint as R1/R2/R4)
  float* ws     = (float*)d_ws;
  float* xz     = ws;                      //  8,388,608 f (y_bf reuses xp head)
  float* xcbf_f = xz + 8388608;            //  2,097,152 f (xc_bf: 4.2M bf16)
  float* proj   = xcbf_f + 2097152;        //    262,144 f
  float* dtb    = proj + 262144;           //  4,194,304 f (pp overlaps head)
  float* T      = dtb + 4194304;           //  2,097,152 f
  float* E      = T + 2097152;             //  2,097,152 f
  float* hbf_f  = E + 2097152;             //  1,048,576 f (h_bf)
  float* wbf    = hbf_f + 1048576;         //    819,200 f (bf16 weights)

  __hip_bfloat16* xc_bf = (__hip_bfloat16*)xcbf_f;
  float* pp = dtb;                         // 1,048,576 f split-K partials
  __hip_bfloat16* h_bf  = (__hip_bfloat16*)hbf_f;
  __hip_bfloat16* Wb_in = (__hip_bfloat16*)wbf;
  __hip_bfloat16* Wb_xp = Wb_in + 1048576;
  __hip_bfloat16* Wb_out = Wb_xp + 65536;
  __hip_bfloat16* y_bf  = (__hip_bfloat16*)xz;   // lda = 4096 shorts

  // 0. weights -> bf16
  cvt3_kernel<<<1600, 256, 0, stream>>>(W_in, W_xprj, W_out, Wb_in, Wb_xp, Wb_out);
  // 1. LayerNorm -> bf16 h
  ln_kernel<<<BL, 64, 0, stream>>>(x, ln_g, ln_b, h_bf);
  // 2. xz = h @ W_in^T   (M=4096, N=2048, K=512)  [MFMA 128x128]
  gemm_mfma_128<false><<<dim3(2 * DINNER / 128, BL / 128), 256, 0, stream>>>(
      h_bf, DIM_, Wb_in, DIM_, nullptr, 0, xz, 2 * DINNER, DIM_);
  // 3. conv + SiLU -> xc_bf; gate = SiLU(z) in place
  conv_silu_kernel<<<(BL * DINNER / 4) / 256, 256, 0, stream>>>(
      xz, conv_w, conv_b, xc_bf);
  // 4. proj = xc @ W_xproj^T (M=4096, N=64, K=1024)  [MFMA 64x64, split-K=4]
  gemm_mfma_64<false><<<dim3(1, BL / 64, 4), 256, 0, stream>>>(
      xc_bf, DINNER, Wb_xp, DINNER, nullptr, 0, pp, 64, 256, 262144);
  reduce4_kernel<<<1024, 256, 0, stream>>>(pp, proj);
  // 5. dt = softplus(proj[:, :32] @ W_dt^T + b_dt)  (overwrites pp region)
  dt_kernel<<<(BL / 16) * 4, 256, 0, stream>>>(proj, W_dt, b_dt, dtb);
  // 6. chunked scan: 64 chunks of 32
  scan1_kernel<<<B_ * NCHUNK * 64, 256, 0, stream>>>(dtb, xc_bf, proj, A_log, T, E);
  combine_kernel<<<(B_ * DINNER * 16) / 256, 256, 0, stream>>>(T, E);
  scan2_kernel<<<B_ * NCHUNK * 4, 256, 0, stream>>>(dtb, xc_bf, proj, A_log, T, Dp, xz);
  // 7. out = x + y @ W_out^T (M=4096, N=512, K=1024)  [MFMA 64x64, fused res]
  gemm_mfma_64<true><<<dim3(DIM_ / 64, BL / 64, 1), 256, 0, stream>>>(
      y_bf, 4096, Wb_out, DINNER, x, DIM_, out, DIM_, DINNER, 0);
}

// Round 6
// 236.752 us; speedup vs baseline: 1.3751x; 1.0700x over previous
//
#include <hip/hip_runtime.h>
#include <hip/hip_bf16.h>
#include <math.h>

#define B_      2
#define L_      2048
#define DIM_    512
#define DINNER  1024
#define DTRANK  32
#define DSTATE  16
#define DCONV   4
#define BL      (B_ * L_)        // 4096
#define NCHUNK  64
#define CLEN    (L_ / NCHUNK)    // 32

typedef __attribute__((ext_vector_type(8))) short bf16x8;
typedef __attribute__((ext_vector_type(4))) float f32x4;

static __device__ __forceinline__ unsigned short f2bf(float f) {
  __hip_bfloat16 h = __float2bfloat16(f);
  return *(unsigned short*)&h;
}
static __device__ __forceinline__ float bf2f(unsigned short u) {
  return __uint_as_float(((unsigned int)u) << 16);
}

// ------- merged: weight fp32->bf16 conversion + LayerNorm ------------------
// blocks 0..1599: cvt (4 elems/thread over 1,638,400)
// blocks 1600..2623: LN, 4 rows/block (one wave per row)
__global__ __launch_bounds__(256) void cvt_ln_kernel(
    const float* __restrict__ s0, const float* __restrict__ s1,
    const float* __restrict__ s2, __hip_bfloat16* __restrict__ d0,
    __hip_bfloat16* __restrict__ d1, __hip_bfloat16* __restrict__ d2,
    const float* __restrict__ x, const float* __restrict__ g,
    const float* __restrict__ b, __hip_bfloat16* __restrict__ h) {
  int blk = blockIdx.x;
  if (blk < 1600) {
    int i = (blk * 256 + threadIdx.x) * 4;
    const float* s; __hip_bfloat16* d; int off;
    if (i < 1048576)            { s = s0; d = d0; off = i; }
    else if (i < 1048576+65536) { s = s1; d = d1; off = i - 1048576; }
    else                        { s = s2; d = d2; off = i - 1114112; }
    float4 v = *(const float4*)(s + off);
    d[off + 0] = __float2bfloat16(v.x);
    d[off + 1] = __float2bfloat16(v.y);
    d[off + 2] = __float2bfloat16(v.z);
    d[off + 3] = __float2bfloat16(v.w);
    return;
  }
  int row = (blk - 1600) * 4 + (threadIdx.x >> 6);
  int lane = threadIdx.x & 63;
  const float* xr = x + (size_t)row * DIM_;
  float v[8];
  float sum = 0.f;
#pragma unroll
  for (int i = 0; i < 8; i++) { v[i] = xr[lane + i * 64]; sum += v[i]; }
#pragma unroll
  for (int o = 32; o > 0; o >>= 1) sum += __shfl_xor(sum, o, 64);
  float mu = sum * (1.f / DIM_);
  float vs = 0.f;
#pragma unroll
  for (int i = 0; i < 8; i++) { float dd = v[i] - mu; vs += dd * dd; }
#pragma unroll
  for (int o = 32; o > 0; o >>= 1) vs += __shfl_xor(vs, o, 64);
  float rstd = rsqrtf(vs * (1.f / DIM_) + 1e-5f);
  __hip_bfloat16* hr = h + (size_t)row * DIM_;
#pragma unroll
  for (int i = 0; i < 8; i++) {
    int c = lane + i * 64;
    hr[c] = __float2bfloat16((v[i] - mu) * rstd * g[c] + b[c]);
  }
}

// ---------------- bf16 MFMA GEMM, 128x128 tile: C = A[M,K] * B[N,K]^T ------
// OUT_BF16: C is ushort* (bf16), else float*. Optional fp32 residual add.
template <bool ADD_RES, bool OUT_BF16>
__global__ __launch_bounds__(256) void gemm_mfma_128(
    const __hip_bfloat16* __restrict__ A, int lda,
    const __hip_bfloat16* __restrict__ Bw, int ldb,
    const float* __restrict__ Res, int ldr,
    void* __restrict__ C, int ldc, int K) {
  constexpr int LDL = 72;
  __shared__ short As[128 * LDL];
  __shared__ short Bs[128 * LDL];
  int t = threadIdx.x;
  int n0 = blockIdx.x * 128, m0 = blockIdx.y * 128;
  int w = t >> 6, lane = t & 63;
  int wm = (w >> 1) * 64, wn = (w & 1) * 64;
  int l15 = lane & 15, quad = lane >> 4;
  int srow = t >> 3, scol = (t & 7) * 8;
  const short* Ag = (const short*)A + (size_t)(m0 + srow) * lda + scol;
  const short* Bg = (const short*)Bw + (size_t)(n0 + srow) * ldb + scol;
  f32x4 acc[4][4];
#pragma unroll
  for (int i = 0; i < 4; i++)
#pragma unroll
    for (int j = 0; j < 4; j++) acc[i][j] = (f32x4){0.f, 0.f, 0.f, 0.f};
  for (int k0 = 0; k0 < K; k0 += 64) {
    __syncthreads();
#pragma unroll
    for (int p = 0; p < 4; p++) {
      *(bf16x8*)&As[(srow + p * 32) * LDL + scol] =
          *(const bf16x8*)(Ag + (size_t)(p * 32) * lda + k0);
      *(bf16x8*)&Bs[(srow + p * 32) * LDL + scol] =
          *(const bf16x8*)(Bg + (size_t)(p * 32) * ldb + k0);
    }
    __syncthreads();
#pragma unroll
    for (int kk = 0; kk < 64; kk += 32) {
      bf16x8 af[4], bfr[4];
#pragma unroll
      for (int i = 0; i < 4; i++) {
        af[i] = *(const bf16x8*)&As[(wm + i * 16 + l15) * LDL + kk + quad * 8];
        bfr[i] = *(const bf16x8*)&Bs[(wn + i * 16 + l15) * LDL + kk + quad * 8];
      }
#pragma unroll
      for (int i = 0; i < 4; i++)
#pragma unroll
        for (int j = 0; j < 4; j++)
          acc[i][j] = __builtin_amdgcn_mfma_f32_16x16x32_bf16(
              af[i], bfr[j], acc[i][j], 0, 0, 0);
    }
  }
#pragma unroll
  for (int i = 0; i < 4; i++)
#pragma unroll
    for (int r = 0; r < 4; r++) {
      int row = m0 + wm + i * 16 + quad * 4 + r;
#pragma unroll
      for (int j = 0; j < 4; j++) {
        int col = n0 + wn + j * 16 + l15;
        float v = acc[i][j][r];
        if (ADD_RES) v += Res[(size_t)row * ldr + col];
        if (OUT_BF16)
          ((unsigned short*)C)[(size_t)row * ldc + col] = f2bf(v);
        else
          ((float*)C)[(size_t)row * ldc + col] = v;
      }
    }
}

// ---------------- bf16 MFMA GEMM, 64x64 tile, split-K (for proj) -----------
__global__ __launch_bounds__(256) void gemm_mfma_64(
    const __hip_bfloat16* __restrict__ A, int lda,
    const __hip_bfloat16* __restrict__ Bw, int ldb,
    float* __restrict__ C, int ldc, int K, size_t czs) {
  constexpr int LDL = 72;
  __shared__ short As[64 * LDL];
  __shared__ short Bs[64 * LDL];
  int t = threadIdx.x;
  int n0 = blockIdx.x * 64, m0 = blockIdx.y * 64;
  size_t kbase = (size_t)blockIdx.z * K;
  int w = t >> 6, lane = t & 63;
  int wm = (w >> 1) * 32, wn = (w & 1) * 32;
  int l15 = lane & 15, quad = lane >> 4;
  int srow = t >> 3, scol = (t & 7) * 8;
  const short* Ag = (const short*)A + (size_t)(m0 + srow) * lda + scol + kbase;
  const short* Bg = (const short*)Bw + (size_t)(n0 + srow) * ldb + scol + kbase;
  f32x4 acc[2][2];
#pragma unroll
  for (int i = 0; i < 2; i++)
#pragma unroll
    for (int j = 0; j < 2; j++) acc[i][j] = (f32x4){0.f, 0.f, 0.f, 0.f};
  for (int k0 = 0; k0 < K; k0 += 64) {
    __syncthreads();
#pragma unroll
    for (int p = 0; p < 2; p++) {
      *(bf16x8*)&As[(srow + p * 32) * LDL + scol] =
          *(const bf16x8*)(Ag + (size_t)(p * 32) * lda + k0);
      *(bf16x8*)&Bs[(srow + p * 32) * LDL + scol] =
          *(const bf16x8*)(Bg + (size_t)(p * 32) * ldb + k0);
    }
    __syncthreads();
#pragma unroll
    for (int kk = 0; kk < 64; kk += 32) {
      bf16x8 af[2], bfr[2];
#pragma unroll
      for (int i = 0; i < 2; i++) {
        af[i] = *(const bf16x8*)&As[(wm + i * 16 + l15) * LDL + kk + quad * 8];
        bfr[i] = *(const bf16x8*)&Bs[(wn + i * 16 + l15) * LDL + kk + quad * 8];
      }
#pragma unroll
      for (int i = 0; i < 2; i++)
#pragma unroll
        for (int j = 0; j < 2; j++)
          acc[i][j] = __builtin_amdgcn_mfma_f32_16x16x32_bf16(
              af[i], bfr[j], acc[i][j], 0, 0, 0);
    }
  }
  float* Cz = C + czs * blockIdx.z;
#pragma unroll
  for (int i = 0; i < 2; i++)
#pragma unroll
    for (int r = 0; r < 4; r++) {
      int row = m0 + wm + i * 16 + quad * 4 + r;
#pragma unroll
      for (int j = 0; j < 2; j++) {
        int col = n0 + wn + j * 16 + l15;
        Cz[(size_t)row * ldc + col] = acc[i][j][r];
      }
    }
}

// ---------------- split-K reduce for proj: proj = sum of 4 slices ----------
__global__ __launch_bounds__(256) void reduce4_kernel(
    const float* __restrict__ pp, float* __restrict__ proj) {
  int i = blockIdx.x * 256 + threadIdx.x;   // over 262144
  proj[i] = pp[i] + pp[i + 262144] + pp[i + 2 * 262144] + pp[i + 3 * 262144];
}

// ------- causal depthwise conv (4 taps) + SiLU over bf16 xz ----------------
// reads xz (bf16 [4096][2048]); writes xc_bf; gate = SiLU(z) bf16 in place.
__global__ __launch_bounds__(256) void conv_silu_kernel(
    unsigned short* __restrict__ xzb, const float* __restrict__ cw,
    const float* __restrict__ cb, __hip_bfloat16* __restrict__ xc_bf) {
  int idx = blockIdx.x * 256 + threadIdx.x;   // over BL*DINNER/4
  int d4 = (idx & 255) * 4;
  int bl = idx >> 8;
  int l = bl & (L_ - 1);
  unsigned short* base = xzb + (size_t)bl * 2048 + d4;
  float4 acc = *(const float4*)(cb + d4);
  float4 w0 = *(const float4*)(cw + (d4 + 0) * 4);
  float4 w1 = *(const float4*)(cw + (d4 + 1) * 4);
  float4 w2 = *(const float4*)(cw + (d4 + 2) * 4);
  float4 w3 = *(const float4*)(cw + (d4 + 3) * 4);
  if (l >= 3) {
    ushort4 r = *(const ushort4*)(base - 3 * 2048);
    acc.x += bf2f(r.x) * w0.x; acc.y += bf2f(r.y) * w1.x;
    acc.z += bf2f(r.z) * w2.x; acc.w += bf2f(r.w) * w3.x;
  }
  if (l >= 2) {
    ushort4 r = *(const ushort4*)(base - 2 * 2048);
    acc.x += bf2f(r.x) * w0.y; acc.y += bf2f(r.y) * w1.y;
    acc.z += bf2f(r.z) * w2.y; acc.w += bf2f(r.w) * w3.y;
  }
  if (l >= 1) {
    ushort4 r = *(const ushort4*)(base - 1 * 2048);
    acc.x += bf2f(r.x) * w0.z; acc.y += bf2f(r.y) * w1.z;
    acc.z += bf2f(r.z) * w2.z; acc.w += bf2f(r.w) * w3.z;
  }
  {
    ushort4 r = *(const ushort4*)(base);
    acc.x += bf2f(r.x) * w0.w; acc.y += bf2f(r.y) * w1.w;
    acc.z += bf2f(r.z) * w2.w; acc.w += bf2f(r.w) * w3.w;
  }
  float4 v;
  v.x = acc.x / (1.f + __expf(-acc.x));
  v.y = acc.y / (1.f + __expf(-acc.y));
  v.z = acc.z / (1.f + __expf(-acc.z));
  v.w = acc.w / (1.f + __expf(-acc.w));
  ushort4 hb;
  hb.x = f2bf(v.x); hb.y = f2bf(v.y); hb.z = f2bf(v.z); hb.w = f2bf(v.w);
  *(ushort4*)(xc_bf + (size_t)bl * DINNER + d4) = hb;
  // gate = SiLU(z), bf16 in place
  ushort4 zu = *(const ushort4*)(base + DINNER);
  float z0 = bf2f(zu.x), z1 = bf2f(zu.y), z2 = bf2f(zu.z), z3 = bf2f(zu.w);
  ushort4 gu;
  gu.x = f2bf(z0 / (1.f + __expf(-z0)));
  gu.y = f2bf(z1 / (1.f + __expf(-z1)));
  gu.z = f2bf(z2 / (1.f + __expf(-z2)));
  gu.w = f2bf(z3 / (1.f + __expf(-z3)));
  *(ushort4*)(base + DINNER) = gu;
}

// ---------------- dt = softplus(proj[:, :32] @ W_dt^T + b_dt) --------------
__global__ __launch_bounds__(256) void dt_kernel(
    const float* __restrict__ proj, const float* __restrict__ Wdt,
    const float* __restrict__ bdt, float* __restrict__ dt) {
  int blk = blockIdx.x;
  int dgrp = blk & 3;
  int bl0 = (blk >> 2) * 16;
  int d = dgrp * 256 + threadIdx.x;
  __shared__ float pr[16 * 32];
  for (int i = threadIdx.x; i < 16 * 32; i += 256) {
    int row = i >> 5, col = i & 31;
    pr[i] = proj[(size_t)(bl0 + row) * 64 + col];
  }
  float w[32];
#pragma unroll
  for (int r4 = 0; r4 < 8; r4++) {
    float4 wv = *(const float4*)(Wdt + (size_t)d * 32 + r4 * 4);
    w[r4 * 4 + 0] = wv.x; w[r4 * 4 + 1] = wv.y;
    w[r4 * 4 + 2] = wv.z; w[r4 * 4 + 3] = wv.w;
  }
  float bias = bdt[d];
  __syncthreads();
  for (int row = 0; row < 16; row++) {
    float acc = bias;
#pragma unroll
    for (int r4 = 0; r4 < 8; r4++) {
      float4 pv = *(const float4*)&pr[row * 32 + r4 * 4];
      acc += pv.x * w[r4 * 4 + 0] + pv.y * w[r4 * 4 + 1] +
             pv.z * w[r4 * 4 + 2] + pv.w * w[r4 * 4 + 3];
    }
    float sp = (acc > 20.f) ? acc : log1pf(__expf(acc));
    dt[(size_t)(bl0 + row) * DINNER + d] = sp;
  }
}

// ---- scan pass 1, (d,n)-parallel: per-chunk decay T and end-state E -------
__global__ __launch_bounds__(256) void scan1_kernel(
    const float* __restrict__ dt, const __hip_bfloat16* __restrict__ xc_bf,
    const float* __restrict__ proj, const float* __restrict__ A_log,
    float* __restrict__ T, float* __restrict__ E) {
  int bid = blockIdx.x;
  int dgrp = bid & 63;
  int c = (bid >> 6) & (NCHUNK - 1);
  int b = bid >> 12;
  int n = threadIdx.x & 15;
  int d = dgrp * 16 + (threadIdx.x >> 4);
  float Aa = -__expf(A_log[(size_t)d * 16 + n]);
  float Tn = 1.f, En = 0.f;
  int l0 = c * CLEN;
  for (int l = l0; l < l0 + CLEN; l++) {
    int bl = b * L_ + l;
    float dtv = dt[(size_t)bl * DINNER + d];
    float xv = __bfloat162float(xc_bf[(size_t)bl * DINNER + d]);
    float Bv = proj[(size_t)bl * 64 + 32 + n];
    float dA = __expf(dtv * Aa);
    Tn *= dA;
    En = En * dA + dtv * xv * Bv;
  }
  size_t o = (((size_t)b * NCHUNK + c) * DINNER + d) * 16 + n;
  T[o] = Tn; E[o] = En;
}

// ---------------- chunk combine over 64 chunks, 4 register-batches of 16 ----
__global__ __launch_bounds__(256) void combine_kernel(
    float* __restrict__ T, const float* __restrict__ E) {
  int idx = blockIdx.x * 256 + threadIdx.x;   // over B*DINNER*16 = 32768
  int b = idx >> 14;
  int dn = idx & 16383;
  size_t base = (size_t)b * NCHUNK * (DINNER * 16) + dn;
  float s = 0.f;
#pragma unroll
  for (int batch = 0; batch < 4; batch++) {
    float t[16], e[16];
#pragma unroll
    for (int j = 0; j < 16; j++) {
      size_t o = base + (size_t)(batch * 16 + j) * (DINNER * 16);
      t[j] = T[o]; e[j] = E[o];
    }
#pragma unroll
    for (int j = 0; j < 16; j++) {
      T[base + (size_t)(batch * 16 + j) * (DINNER * 16)] = s;
      s = t[j] * s + e[j];
    }
  }
}

// ---- scan pass 2: 16 states per thread, in-register y reduction -----------
// gate read bf16 (cols 1024..2047 of xz); y written bf16 to cols 0..1023.
__global__ __launch_bounds__(256) void scan2_kernel(
    const float* __restrict__ dt, const __hip_bfloat16* __restrict__ xc_bf,
    const float* __restrict__ proj, const float* __restrict__ A_log,
    const float* __restrict__ Sstart, const float* __restrict__ Dp,
    unsigned short* __restrict__ xzb) {
  int bid = blockIdx.x;
  int dgrp = bid & 3;
  int c = (bid >> 2) & (NCHUNK - 1);
  int b = bid >> 8;
  int d = dgrp * 256 + threadIdx.x;
  int l0 = c * CLEN;
  __shared__ float Bs[CLEN * 16];
  __shared__ float Cs[CLEN * 16];
  for (int i = threadIdx.x; i < CLEN * 16; i += 256) {
    int row = i >> 4, nn = i & 15;
    const float* pr = proj + (size_t)(b * L_ + l0 + row) * 64;
    Bs[i] = pr[32 + nn];
    Cs[i] = pr[48 + nn];
  }
  float Aa[16], s[16];
  size_t sb = (((size_t)b * NCHUNK + c) * DINNER + d) * 16;
#pragma unroll
  for (int q = 0; q < 4; q++) {
    float4 av = *(const float4*)(A_log + (size_t)d * 16 + q * 4);
    Aa[q * 4 + 0] = -__expf(av.x); Aa[q * 4 + 1] = -__expf(av.y);
    Aa[q * 4 + 2] = -__expf(av.z); Aa[q * 4 + 3] = -__expf(av.w);
    float4 sv = *(const float4*)(Sstart + sb + q * 4);
    s[q * 4 + 0] = sv.x; s[q * 4 + 1] = sv.y;
    s[q * 4 + 2] = sv.z; s[q * 4 + 3] = sv.w;
  }
  float Dv = Dp[d];
  __syncthreads();
  for (int l = l0; l < l0 + CLEN; l++) {
    int bl = b * L_ + l;
    float dtv = dt[(size_t)bl * DINNER + d];
    float xv = __bfloat162float(xc_bf[(size_t)bl * DINNER + d]);
    float dx = dtv * xv;
    int lrow = (l - l0) * 16;
    float y = 0.f;
#pragma unroll
    for (int n = 0; n < 16; n++) {
      float dA = __expf(dtv * Aa[n]);
      s[n] = s[n] * dA + dx * Bs[lrow + n];
      y += s[n] * Cs[lrow + n];
    }
    float gate = bf2f(xzb[(size_t)bl * 2048 + 1024 + d]);
    xzb[(size_t)bl * 2048 + d] = f2bf((y + xv * Dv) * gate);
  }
}

extern "C" void kernel_launch(void* const* d_in, const int* in_sizes, int n_in,
                              void* d_out, int out_size, void* d_ws, size_t ws_size,
                              hipStream_t stream) {
  const float* x      = (const float*)d_in[0];
  const float* ln_g   = (const float*)d_in[1];
  const float* ln_b   = (const float*)d_in[2];
  const float* W_in   = (const float*)d_in[3];
  const float* conv_w = (const float*)d_in[4];
  const float* conv_b = (const float*)d_in[5];
  const float* W_xprj = (const float*)d_in[6];
  const float* W_dt   = (const float*)d_in[7];
  const float* b_dt   = (const float*)d_in[8];
  const float* A_log  = (const float*)d_in[9];
  const float* Dp     = (const float*)d_in[10];
  const float* W_out  = (const float*)d_in[11];
  float* out = (float*)d_out;

  // workspace layout (floats) — total 67.2 MB
  float* ws     = (float*)d_ws;
  float* xzb_f  = ws;                      //  4,194,304 f (xz bf16 [4096][2048])
  float* xcbf_f = xzb_f + 4194304;         //  2,097,152 f (xc_bf)
  float* proj   = xcbf_f + 2097152;        //    262,144 f
  float* dtb    = proj + 262144;           //  4,194,304 f (pp overlaps head)
  float* T      = dtb + 4194304;           //  2,097,152 f
  float* E      = T + 2097152;             //  2,097,152 f
  float* hbf_f  = E + 2097152;             //  1,048,576 f (h_bf)
  float* wbf    = hbf_f + 1048576;         //    819,200 f (bf16 weights)

  unsigned short* xzb   = (unsigned short*)xzb_f;
  __hip_bfloat16* xc_bf = (__hip_bfloat16*)xcbf_f;
  float* pp = dtb;                         // 1,048,576 f split-K partials
  __hip_bfloat16* h_bf  = (__hip_bfloat16*)hbf_f;
  __hip_bfloat16* Wb_in = (__hip_bfloat16*)wbf;
  __hip_bfloat16* Wb_xp = Wb_in + 1048576;
  __hip_bfloat16* Wb_out = Wb_xp + 65536;
  __hip_bfloat16* y_bf  = (__hip_bfloat16*)xzb;  // cols 0..1023, lda=2048

  // 0+1. weights -> bf16  ∥  LayerNorm -> bf16 h   (one dispatch)
  cvt_ln_kernel<<<1600 + BL / 4, 256, 0, stream>>>(
      W_in, W_xprj, W_out, Wb_in, Wb_xp, Wb_out, x, ln_g, ln_b, h_bf);
  // 2. xz = h @ W_in^T  (M=4096, N=2048, K=512) -> bf16 [MFMA 128x128]
  gemm_mfma_128<false, true><<<dim3(2 * DINNER / 128, BL / 128), 256, 0, stream>>>(
      h_bf, DIM_, Wb_in, DIM_, nullptr, 0, xzb, 2 * DINNER, DIM_);
  // 3. conv + SiLU -> xc_bf; gate = SiLU(z) bf16 in place
  conv_silu_kernel<<<(BL * DINNER / 4) / 256, 256, 0, stream>>>(
      xzb, conv_w, conv_b, xc_bf);
  // 4. proj = xc @ W_xproj^T (M=4096, N=64, K=1024)  [MFMA 64x64, split-K=4]
  gemm_mfma_64<<<dim3(1, BL / 64, 4), 256, 0, stream>>>(
      xc_bf, DINNER, Wb_xp, DINNER, pp, 64, 256, 262144);
  reduce4_kernel<<<1024, 256, 0, stream>>>(pp, proj);
  // 5. dt = softplus(proj[:, :32] @ W_dt^T + b_dt)  (overwrites pp region)
  dt_kernel<<<(BL / 16) * 4, 256, 0, stream>>>(proj, W_dt, b_dt, dtb);
  // 6. chunked scan: 64 chunks of 32
  scan1_kernel<<<B_ * NCHUNK * 64, 256, 0, stream>>>(dtb, xc_bf, proj, A_log, T, E);
  combine_kernel<<<(B_ * DINNER * 16) / 256, 256, 0, stream>>>(T, E);
  scan2_kernel<<<B_ * NCHUNK * 4, 256, 0, stream>>>(dtb, xc_bf, proj, A_log, T, Dp, xzb);
  // 7. out = x + y @ W_out^T (M=4096, N=512, K=1024)  [MFMA 128x128, res]
  gemm_mfma_128<true, false><<<dim3(DIM_ / 128, BL / 128), 256, 0, stream>>>(
      y_bf, 2048, Wb_out, DINNER, x, DIM_, out, DIM_, DINNER);
}